// Round 1
// baseline (239.849 us; speedup 1.0000x reference)
//
#include <hip/hip_runtime.h>

// LIF spiking recurrence:
//   mem = mem*TAU + x[t]*alpha; spike = (mem > Vth); mem = spike ? 0 : mem
// Recurrence only along T (=8); spatial positions independent.
// One thread per float4 (4 spatial positions), mem carried in registers.

#define TAU 0.5f
#define T_STEPS 8

__global__ __launch_bounds__(256) void lif_kernel(
    const float* __restrict__ x,
    const float* __restrict__ alpha_p,
    const float* __restrict__ vth_p,
    float* __restrict__ out,
    int n4)  // number of float4 groups per timestep
{
    const int i = blockIdx.x * blockDim.x + threadIdx.x;
    if (i >= n4) return;

    const float alpha = alpha_p[0];
    const float vth   = vth_p[0];

    const float4* __restrict__ x4   = (const float4*)x;
    float4* __restrict__       out4 = (float4*)out;

    float4 mem = make_float4(0.f, 0.f, 0.f, 0.f);

#pragma unroll
    for (int t = 0; t < T_STEPS; ++t) {
        float4 xt = x4[(size_t)t * n4 + i];

        mem.x = mem.x * TAU + xt.x * alpha;
        mem.y = mem.y * TAU + xt.y * alpha;
        mem.z = mem.z * TAU + xt.z * alpha;
        mem.w = mem.w * TAU + xt.w * alpha;

        float4 sp;
        sp.x = (mem.x > vth) ? 1.f : 0.f;
        sp.y = (mem.y > vth) ? 1.f : 0.f;
        sp.z = (mem.z > vth) ? 1.f : 0.f;
        sp.w = (mem.w > vth) ? 1.f : 0.f;

        // hard reset on spike
        mem.x = (sp.x > 0.f) ? 0.f : mem.x;
        mem.y = (sp.y > 0.f) ? 0.f : mem.y;
        mem.z = (sp.z > 0.f) ? 0.f : mem.z;
        mem.w = (sp.w > 0.f) ? 0.f : mem.w;

        out4[(size_t)t * n4 + i] = sp;
    }
}

extern "C" void kernel_launch(void* const* d_in, const int* in_sizes, int n_in,
                              void* d_out, int out_size, void* d_ws, size_t ws_size,
                              hipStream_t stream) {
    const float* x     = (const float*)d_in[0];
    const float* alpha = (const float*)d_in[1];
    const float* vth   = (const float*)d_in[2];
    float* out         = (float*)d_out;

    const int total = in_sizes[0];          // T * B * C * H * W
    const int n     = total / T_STEPS;      // spatial elements per timestep
    const int n4    = n / 4;                // float4 groups per timestep

    const int block = 256;
    const int grid  = (n4 + block - 1) / block;
    lif_kernel<<<grid, block, 0, stream>>>(x, alpha, vth, out, n4);
}

// Round 3
// 233.764 us; speedup vs baseline: 1.0260x; 1.0260x over previous
//
#include <hip/hip_runtime.h>

// LIF spiking recurrence over T=8:
//   mem = mem*TAU + x[t]*alpha; spike = (mem > Vth); mem = spike ? 0 : mem
// One thread per float4 (4 spatial positions).
// R3: same as R2 (hoisted loads for MLP=8 + nontemporal hints) but with a
// native clang ext_vector float4 — __builtin_nontemporal_* rejects HIP's
// float4 class type.

#define TAU 0.5f
#define T_STEPS 8

typedef float vf4 __attribute__((ext_vector_type(4)));

__global__ __launch_bounds__(256) void lif_kernel(
    const float* __restrict__ x,
    const float* __restrict__ alpha_p,
    const float* __restrict__ vth_p,
    float* __restrict__ out,
    int n4)  // float4 groups per timestep
{
    const int i = blockIdx.x * blockDim.x + threadIdx.x;
    if (i >= n4) return;

    const float alpha = alpha_p[0];
    const float vth   = vth_p[0];

    const vf4* __restrict__ x4   = (const vf4*)x;
    vf4* __restrict__       out4 = (vf4*)out;

    // Issue all 8 loads back-to-back: 8 outstanding HBM loads per thread.
    vf4 xt[T_STEPS];
#pragma unroll
    for (int t = 0; t < T_STEPS; ++t) {
        xt[t] = __builtin_nontemporal_load(&x4[(size_t)t * n4 + i]);
    }

    vf4 mem = (vf4)(0.f);

#pragma unroll
    for (int t = 0; t < T_STEPS; ++t) {
        mem = mem * TAU + xt[t] * alpha;

        vf4 sp;
        sp.x = (mem.x > vth) ? 1.f : 0.f;
        sp.y = (mem.y > vth) ? 1.f : 0.f;
        sp.z = (mem.z > vth) ? 1.f : 0.f;
        sp.w = (mem.w > vth) ? 1.f : 0.f;

        mem.x = (sp.x > 0.f) ? 0.f : mem.x;
        mem.y = (sp.y > 0.f) ? 0.f : mem.y;
        mem.z = (sp.z > 0.f) ? 0.f : mem.z;
        mem.w = (sp.w > 0.f) ? 0.f : mem.w;

        __builtin_nontemporal_store(sp, &out4[(size_t)t * n4 + i]);
    }
}

extern "C" void kernel_launch(void* const* d_in, const int* in_sizes, int n_in,
                              void* d_out, int out_size, void* d_ws, size_t ws_size,
                              hipStream_t stream) {
    const float* x     = (const float*)d_in[0];
    const float* alpha = (const float*)d_in[1];
    const float* vth   = (const float*)d_in[2];
    float* out         = (float*)d_out;

    const int total = in_sizes[0];          // T * B * C * H * W
    const int n     = total / T_STEPS;      // spatial elements per timestep
    const int n4    = n / 4;                // float4 groups per timestep

    const int block = 256;
    const int grid  = (n4 + block - 1) / block;
    lif_kernel<<<grid, block, 0, stream>>>(x, alpha, vth, out, n4);
}